// Round 4
// baseline (1121.748 us; speedup 1.0000x reference)
//
#include <hip/hip_runtime.h>
#include <hip/hip_bf16.h>

typedef __bf16 bf16x8 __attribute__((ext_vector_type(8)));
typedef float  f32x4  __attribute__((ext_vector_type(4)));
typedef unsigned short u16x8 __attribute__((ext_vector_type(8)));

#define CH    256
#define IMG   112
#define WSZ   7
#define TOK   49
#define NWIN  4096
#define HID   512

#define SX_ST 260          // f32 row stride for sX / sW staging

// ---- LDS arena (byte offsets), time-multiplexed ----
#define OFF_V    0
#define OFF_AF   51200
#define OFF_P    51200
#define PSZ      7168
#define OFF_Q    83968
#define OFF_HM   83968
#define OFF_K    116736
#define OFF_OF   116736
#define OFF_MR   149504     // sM[64], sR[64]
#define OFF_PRM  150016     // sG1,sB1,sG2,sB2 (each 256 f32)
#define SMEM_SZ  154112

// ---- d_ws layout: bf16 B-fragment blocks, 1KB each ----
#define WS_PROJ_BLK 384
#define WS_W1_BLK   512
#define WS_W2_BLK   768

__device__ __forceinline__ unsigned short f2bf(float f) {
    __bf16 h = (__bf16)f;
    return __builtin_bit_cast(unsigned short, h);
}

__device__ __forceinline__ f32x4 mfma16(bf16x8 a, bf16x8 b, f32x4 c) {
    return __builtin_amdgcn_mfma_f32_16x16x32_bf16(a, b, c, 0, 0, 0);
}

__device__ __forceinline__ int frOff(int base, int t, int c) {
    return base + (((t >> 4) * 8 + (c >> 5)) << 10)
                + (((((c >> 3) & 3) << 4) | (t & 15)) << 4)
                + ((c & 7) << 1);
}
__device__ __forceinline__ int frOffT(int base, int c, int t) {
    return base + ((((c >> 4) << 1) + (t >> 5)) << 10)
                + (((((t >> 3) & 3) << 4) | (c & 15)) << 4)
                + ((t & 7) << 1);
}

// ---------------- prepack: fp32 weights -> bf16 B-fragment blocks in d_ws ----------------
extern "C" __global__ __launch_bounds__(64)
void prepack(const float* __restrict__ qkv_w, const float* __restrict__ proj_w,
             const float* __restrict__ w1, const float* __restrict__ w2,
             char* __restrict__ ws)
{
    const int blk = blockIdx.x, l = threadIdx.x;
    const float* W; int nt, kt, ncols;
    if (blk < WS_PROJ_BLK)      { W = qkv_w;  int i = blk;               nt = i >> 3; kt = i & 7;  ncols = 768; }
    else if (blk < WS_W1_BLK)   { W = proj_w; int i = blk - WS_PROJ_BLK; nt = i >> 3; kt = i & 7;  ncols = 256; }
    else if (blk < WS_W2_BLK)   { W = w1;     int i = blk - WS_W1_BLK;   nt = i >> 3; kt = i & 7;  ncols = 512; }
    else                        { W = w2;     int i = blk - WS_W2_BLK;   nt = i >> 4; kt = i & 15; ncols = 256; }
    const int n  = nt * 16 + (l & 15);
    const int k0 = kt * 32 + (l >> 4) * 8;
    u16x8 o;
    #pragma unroll
    for (int j = 0; j < 8; ++j) o[j] = f2bf(W[(size_t)(k0 + j) * ncols + n]);
    *(u16x8*)(ws + (size_t)blk * 1024 + l * 16) = o;
}

// ---------------- main fused block: 16 waves ----------------
extern "C" __global__ __launch_bounds__(1024, 1)
void swin_block(const float* __restrict__ x,
                const float* __restrict__ ln1_g, const float* __restrict__ ln1_b,
                const float* __restrict__ qkv_b,
                const float* __restrict__ proj_b,
                const float* __restrict__ ln2_g, const float* __restrict__ ln2_b,
                const float* __restrict__ b1, const float* __restrict__ b2,
                const char* __restrict__ ws,
                float* __restrict__ y)
{
    __shared__ __align__(16) char smem[SMEM_SZ];
    float* sX = (float*)(smem + 0);          // also sW later
    float* sM = (float*)(smem + OFF_MR);
    float* sR = sM + 64;
    float* sG1 = (float*)(smem + OFF_PRM);
    float* sB1 = sG1 + 256;
    float* sG2 = sB1 + 256;
    float* sB2 = sG2 + 256;

    const int tid  = threadIdx.x;
    const int wid  = tid >> 6;       // 0..15
    const int lane = tid & 63;
    const int sub  = lane >> 4;
    const int l15  = lane & 15;
    const int mg   = wid >> 3;       // m-group 0..1 (row-tiles mg*2, mg*2+1)
    const int ng   = wid & 7;        // n-group 0..7

    const int n  = blockIdx.x;
    const int b  = n >> 8;
    const int wh = (n >> 4) & 15;
    const int ww = n & 15;
    const int row0 = wh * WSZ, col0 = ww * WSZ;
    const size_t xbase = (size_t)b * CH * IMG * IMG;

    const f32x4 z4 = {0.f, 0.f, 0.f, 0.f};

    // ---- P0: stage x -> sX; load LN params ----
    for (int e = tid; e < TOK * CH; e += 1024) {
        int j = e % 7; int rem = e / 7; int i = rem % 7; int c = rem / 7;
        sX[(i * 7 + j) * SX_ST + c] = x[xbase + ((size_t)c * IMG + row0 + i) * IMG + col0 + j];
    }
    if (tid < 512) {
        int t2 = tid & 255;
        if (tid < 256) { sG1[t2] = ln1_g[t2]; sB1[t2] = ln1_b[t2]; }
        else           { sG2[t2] = ln2_g[t2]; sB2[t2] = ln2_b[t2]; }
    }
    __syncthreads();   // 1

    // ---- P1: LN1 stats ----
    for (int t = wid; t < TOK; t += 16) {
        const float4 v = *(const float4*)&sX[t * SX_ST + lane * 4];
        float s1 = v.x + v.y + v.z + v.w;
        float s2 = v.x * v.x + v.y * v.y + v.z * v.z + v.w * v.w;
        #pragma unroll
        for (int off = 32; off > 0; off >>= 1) {
            s1 += __shfl_xor(s1, off);
            s2 += __shfl_xor(s2, off);
        }
        if (lane == 0) {
            float m = s1 * (1.f / 256.f);
            float var = s2 * (1.f / 256.f) - m * m;
            sM[t] = m; sR[t] = rsqrtf(var + 1e-5f);
        }
    }
    __syncthreads();   // 2

    // ---- P2: normalize -> n1F fragment blocks; zero pad rows ----
    for (int e = tid; e < 2048; e += 1024) {
        int t = e & 63, cb = e >> 6;
        char* dst = smem + OFF_AF + (((t >> 4) * 8 + (cb >> 2)) << 10)
                  + (((((cb & 3) << 4) | (t & 15))) << 4);
        if (t < TOK) {
            const float* xr = sX + t * SX_ST + cb * 8;
            float4 xa = *(const float4*)xr;
            float4 xb = *(const float4*)(xr + 4);
            float m = sM[t], rs = sR[t];
            int c = cb * 8;
            u16x8 o;
            o[0] = f2bf((xa.x - m) * rs * sG1[c + 0] + sB1[c + 0]);
            o[1] = f2bf((xa.y - m) * rs * sG1[c + 1] + sB1[c + 1]);
            o[2] = f2bf((xa.z - m) * rs * sG1[c + 2] + sB1[c + 2]);
            o[3] = f2bf((xa.w - m) * rs * sG1[c + 3] + sB1[c + 3]);
            o[4] = f2bf((xb.x - m) * rs * sG1[c + 4] + sB1[c + 4]);
            o[5] = f2bf((xb.y - m) * rs * sG1[c + 5] + sB1[c + 5]);
            o[6] = f2bf((xb.z - m) * rs * sG1[c + 6] + sB1[c + 6]);
            o[7] = f2bf((xb.w - m) * rs * sG1[c + 7] + sB1[c + 7]);
            *(u16x8*)dst = o;
        } else {
            u16x8 z = {0, 0, 0, 0, 0, 0, 0, 0};
            *(u16x8*)dst = z;
        }
    }
    __syncthreads();   // 3

    // ---- P3: QKV GEMM (M=64,N=768,K=256); wave (mg,ng): ntg = ng*6 + i ----
    {
        bf16x8 aF[2][8];
        #pragma unroll
        for (int m = 0; m < 2; ++m)
            #pragma unroll
            for (int kt = 0; kt < 8; ++kt)
                aF[m][kt] = *(const bf16x8*)(smem + OFF_AF + (((mg * 2 + m) * 8 + kt) << 10) + lane * 16);

        auto qkv_epi = [&](int ntg, const f32x4 (&acc)[2]) {
            const float bias = qkv_b[ntg * 16 + l15];
            const int m3 = ntg >> 4;              // 0=Q 1=K 2=V
            const int c = (ntg & 15) * 16 + l15;
            if (m3 == 2) {
                #pragma unroll
                for (int m = 0; m < 2; ++m)
                    #pragma unroll
                    for (int r = 0; r < 4; ++r) {
                        int t = (mg * 2 + m) * 16 + sub * 4 + r;
                        *(unsigned short*)(smem + frOffT(OFF_V, c, t)) = f2bf(acc[m][r] + bias);
                    }
            } else if (m3 == 1) {
                #pragma unroll
                for (int m = 0; m < 2; ++m)
                    #pragma unroll
                    for (int r = 0; r < 4; ++r) {
                        int t = (mg * 2 + m) * 16 + sub * 4 + r;
                        *(unsigned short*)(smem + frOff(OFF_K, t, c)) = f2bf(acc[m][r] + bias);
                    }
            } else {
                #pragma unroll
                for (int m = 0; m < 2; ++m)
                    #pragma unroll
                    for (int r = 0; r < 4; ++r) {
                        int t = (mg * 2 + m) * 16 + sub * 4 + r;
                        *(unsigned short*)(smem + frOff(OFF_Q, t, c)) = f2bf((acc[m][r] + bias) * 0.125f);
                    }
            }
        };

        bf16x8 bA[8], bB[8];
        #pragma unroll
        for (int kt = 0; kt < 8; ++kt)
            bA[kt] = *(const bf16x8*)(ws + (size_t)(((ng * 6) * 8 + kt) << 10) + lane * 16);

        for (int i = 0; i < 6; i += 2) {
            const int n0 = ng * 6 + i;
            #pragma unroll
            for (int kt = 0; kt < 8; ++kt)
                bB[kt] = *(const bf16x8*)(ws + (size_t)(((n0 + 1) * 8 + kt) << 10) + lane * 16);
            {
                f32x4 acc[2] = {z4, z4};
                #pragma unroll
                for (int kt = 0; kt < 8; ++kt)
                    #pragma unroll
                    for (int m = 0; m < 2; ++m)
                        acc[m] = mfma16(aF[m][kt], bA[kt], acc[m]);
                qkv_epi(n0, acc);
            }
            if (i + 2 < 6) {
                #pragma unroll
                for (int kt = 0; kt < 8; ++kt)
                    bA[kt] = *(const bf16x8*)(ws + (size_t)(((n0 + 2) * 8 + kt) << 10) + lane * 16);
            }
            {
                f32x4 acc[2] = {z4, z4};
                #pragma unroll
                for (int kt = 0; kt < 8; ++kt)
                    #pragma unroll
                    for (int m = 0; m < 2; ++m)
                        acc[m] = mfma16(aF[m][kt], bB[kt], acc[m]);
                qkv_epi(n0 + 1, acc);
            }
        }
    }
    __syncthreads();   // 4

    // ---- P4: attention; wave = (head h = wid>>2, m-quarter ah = wid&3) ----
    {
        const int h  = wid >> 2;
        const int ah = wid & 3;
        bf16x8 qf[2], kf[4][2];
        #pragma unroll
        for (int k2 = 0; k2 < 2; ++k2)
            qf[k2] = *(const bf16x8*)(smem + OFF_Q + ((ah * 8 + h * 2 + k2) << 10) + lane * 16);
        #pragma unroll
        for (int nt = 0; nt < 4; ++nt)
            #pragma unroll
            for (int k2 = 0; k2 < 2; ++k2)
                kf[nt][k2] = *(const bf16x8*)(smem + OFF_K + ((nt * 8 + h * 2 + k2) << 10) + lane * 16);

        f32x4 sc[4];
        #pragma unroll
        for (int nt = 0; nt < 4; ++nt) sc[nt] = z4;
        #pragma unroll
        for (int k2 = 0; k2 < 2; ++k2)
            #pragma unroll
            for (int nt = 0; nt < 4; ++nt)
                sc[nt] = mfma16(qf[k2], kf[nt][k2], sc[nt]);

        const int pbase = OFF_P + h * PSZ;
        #pragma unroll
        for (int r = 0; r < 4; ++r) {
            const int t = ah * 16 + sub * 4 + r;
            float v0 = sc[0][r];
            float v1 = sc[1][r];
            float v2 = sc[2][r];
            float v3 = (l15 == 0) ? sc[3][r] : -1e30f;
            float mx = fmaxf(fmaxf(v0, v1), fmaxf(v2, v3));
            mx = fmaxf(mx, __shfl_xor(mx, 1));
            mx = fmaxf(mx, __shfl_xor(mx, 2));
            mx = fmaxf(mx, __shfl_xor(mx, 4));
            mx = fmaxf(mx, __shfl_xor(mx, 8));
            float e0 = __expf(v0 - mx), e1 = __expf(v1 - mx);
            float e2 = __expf(v2 - mx), e3 = __expf(v3 - mx);
            float s = e0 + e1 + e2 + e3;
            s += __shfl_xor(s, 1);
            s += __shfl_xor(s, 2);
            s += __shfl_xor(s, 4);
            s += __shfl_xor(s, 8);
            float inv = 1.f / s;
            if (t < TOK) {
                unsigned short* pr = (unsigned short*)(smem + pbase + t * 144);
                pr[l15]      = f2bf(e0 * inv);
                pr[16 + l15] = f2bf(e1 * inv);
                pr[32 + l15] = f2bf(e2 * inv);
                pr[48 + l15] = f2bf(e3 * inv);
            }
        }

        // PV: O_h rows of this m-quarter (P rows are wave-local)
        bf16x8 pf[2], vf[4][2];
        #pragma unroll
        for (int k2 = 0; k2 < 2; ++k2) {
            int row = ah * 16 + l15; row = row > 48 ? 48 : row;
            pf[k2] = *(const bf16x8*)(smem + pbase + row * 144 + ((k2 * 32 + sub * 8) << 1));
        }
        #pragma unroll
        for (int nt = 0; nt < 4; ++nt)
            #pragma unroll
            for (int k2 = 0; k2 < 2; ++k2)
                vf[nt][k2] = *(const bf16x8*)(smem + OFF_V + ((((h * 4 + nt) << 1) + k2) << 10) + lane * 16);

        f32x4 oc[4];
        #pragma unroll
        for (int nt = 0; nt < 4; ++nt) oc[nt] = z4;
        #pragma unroll
        for (int k2 = 0; k2 < 2; ++k2)
            #pragma unroll
            for (int nt = 0; nt < 4; ++nt)
                oc[nt] = mfma16(pf[k2], vf[nt][k2], oc[nt]);
        #pragma unroll
        for (int nt = 0; nt < 4; ++nt)
            #pragma unroll
            for (int r = 0; r < 4; ++r) {
                int t = ah * 16 + sub * 4 + r;
                int c = h * 64 + nt * 16 + l15;
                *(unsigned short*)(smem + frOff(OFF_OF, t, c)) = f2bf(oc[nt][r]);
            }
    }
    __syncthreads();   // 5

    // ---- P5: restage x -> sW ----
    float* sW = sX;
    for (int e = tid; e < TOK * CH; e += 1024) {
        int j = e % 7; int rem = e / 7; int i = rem % 7; int c = rem / 7;
        sW[(i * 7 + j) * SX_ST + c] = x[xbase + ((size_t)c * IMG + row0 + i) * IMG + col0 + j];
    }
    __syncthreads();   // 6

    // ---- P6: proj + residual -> sW; wave (mg,ng): ntg = ng*2 + i ----
    {
        bf16x8 aF[2][8];
        #pragma unroll
        for (int m = 0; m < 2; ++m)
            #pragma unroll
            for (int kt = 0; kt < 8; ++kt)
                aF[m][kt] = *(const bf16x8*)(smem + OFF_OF + (((mg * 2 + m) * 8 + kt) << 10) + lane * 16);

        auto proj_epi = [&](int ntg, const f32x4 (&acc)[2]) {
            const int c = ntg * 16 + l15;
            const float bias = proj_b[c];
            #pragma unroll
            for (int m = 0; m < 2; ++m)
                #pragma unroll
                for (int r = 0; r < 4; ++r) {
                    int t = (mg * 2 + m) * 16 + sub * 4 + r;
                    if (t < TOK) sW[t * SX_ST + c] += acc[m][r] + bias;
                }
        };

        bf16x8 bA[8], bB[8];
        #pragma unroll
        for (int kt = 0; kt < 8; ++kt)
            bA[kt] = *(const bf16x8*)(ws + (size_t)(((WS_PROJ_BLK + (ng * 2) * 8 + kt)) << 10) + lane * 16);
        #pragma unroll
        for (int kt = 0; kt < 8; ++kt)
            bB[kt] = *(const bf16x8*)(ws + (size_t)(((WS_PROJ_BLK + (ng * 2 + 1) * 8 + kt)) << 10) + lane * 16);
        {
            f32x4 acc[2] = {z4, z4};
            #pragma unroll
            for (int kt = 0; kt < 8; ++kt)
                #pragma unroll
                for (int m = 0; m < 2; ++m)
                    acc[m] = mfma16(aF[m][kt], bA[kt], acc[m]);
            proj_epi(ng * 2, acc);
        }
        {
            f32x4 acc[2] = {z4, z4};
            #pragma unroll
            for (int kt = 0; kt < 8; ++kt)
                #pragma unroll
                for (int m = 0; m < 2; ++m)
                    acc[m] = mfma16(aF[m][kt], bB[kt], acc[m]);
            proj_epi(ng * 2 + 1, acc);
        }
    }
    __syncthreads();   // 7

    // ---- P7: LN2 stats ----
    for (int t = wid; t < TOK; t += 16) {
        const float4 v = *(const float4*)&sW[t * SX_ST + lane * 4];
        float s1 = v.x + v.y + v.z + v.w;
        float s2 = v.x * v.x + v.y * v.y + v.z * v.z + v.w * v.w;
        #pragma unroll
        for (int off = 32; off > 0; off >>= 1) {
            s1 += __shfl_xor(s1, off);
            s2 += __shfl_xor(s2, off);
        }
        if (lane == 0) {
            float m = s1 * (1.f / 256.f);
            float var = s2 * (1.f / 256.f) - m * m;
            sM[t] = m; sR[t] = rsqrtf(var + 1e-5f);
        }
    }
    __syncthreads();   // 8

    // ---- P8: LN2 normalize -> n2F ----
    for (int e = tid; e < 2048; e += 1024) {
        int t = e & 63, cb = e >> 6;
        char* dst = smem + OFF_AF + (((t >> 4) * 8 + (cb >> 2)) << 10)
                  + (((((cb & 3) << 4) | (t & 15))) << 4);
        if (t < TOK) {
            const float* xr = sW + t * SX_ST + cb * 8;
            float4 xa = *(const float4*)xr;
            float4 xb = *(const float4*)(xr + 4);
            float m = sM[t], rs = sR[t];
            int c = cb * 8;
            u16x8 o;
            o[0] = f2bf((xa.x - m) * rs * sG2[c + 0] + sB2[c + 0]);
            o[1] = f2bf((xa.y - m) * rs * sG2[c + 1] + sB2[c + 1]);
            o[2] = f2bf((xa.z - m) * rs * sG2[c + 2] + sB2[c + 2]);
            o[3] = f2bf((xa.w - m) * rs * sG2[c + 3] + sB2[c + 3]);
            o[4] = f2bf((xb.x - m) * rs * sG2[c + 4] + sB2[c + 4]);
            o[5] = f2bf((xb.y - m) * rs * sG2[c + 5] + sB2[c + 5]);
            o[6] = f2bf((xb.z - m) * rs * sG2[c + 6] + sB2[c + 6]);
            o[7] = f2bf((xb.w - m) * rs * sG2[c + 7] + sB2[c + 7]);
            *(u16x8*)dst = o;
        } else {
            u16x8 z = {0, 0, 0, 0, 0, 0, 0, 0};
            *(u16x8*)dst = z;
        }
    }
    __syncthreads();   // 9

    // ---- P9: MLP in two K-halves; hmid ping-pongs in HM ----
    {
        f32x4 a20[2] = {z4, z4}, a21[2] = {z4, z4};

        for (int half = 0; half < 2; ++half) {
            // MLP1: n2 @ w1[:, half*256 +: 256] + b1, GELU -> HM; ntg = ng*2 + i
            {
                bf16x8 nf[2][8];
                #pragma unroll
                for (int m = 0; m < 2; ++m)
                    #pragma unroll
                    for (int kt = 0; kt < 8; ++kt)
                        nf[m][kt] = *(const bf16x8*)(smem + OFF_AF + (((mg * 2 + m) * 8 + kt) << 10) + lane * 16);

                auto mlp1_epi = [&](int ntg, const f32x4 (&acc)[2]) {
                    const int chm = ntg * 16 + l15;
                    const float bias = b1[half * 256 + chm];
                    #pragma unroll
                    for (int m = 0; m < 2; ++m)
                        #pragma unroll
                        for (int r = 0; r < 4; ++r) {
                            int t = (mg * 2 + m) * 16 + sub * 4 + r;
                            if (t < TOK) {
                                float v = acc[m][r] + bias;
                                float u = v * (1.5957691216f + 0.07135481627f * v * v);
                                float g = v / (1.f + __expf(-u));
                                *(unsigned short*)(smem + frOff(OFF_HM, t, chm)) = f2bf(g);
                            }
                        }
                };

                bf16x8 bA[8], bB[8];
                #pragma unroll
                for (int kt = 0; kt < 8; ++kt)
                    bA[kt] = *(const bf16x8*)(ws + (size_t)(((WS_W1_BLK + (half * 16 + ng * 2) * 8 + kt)) << 10) + lane * 16);
                #pragma unroll
                for (int kt = 0; kt < 8; ++kt)
                    bB[kt] = *(const bf16x8*)(ws + (size_t)(((WS_W1_BLK + (half * 16 + ng * 2 + 1) * 8 + kt)) << 10) + lane * 16);
                {
                    f32x4 acc[2] = {z4, z4};
                    #pragma unroll
                    for (int kt = 0; kt < 8; ++kt)
                        #pragma unroll
                        for (int m = 0; m < 2; ++m)
                            acc[m] = mfma16(nf[m][kt], bA[kt], acc[m]);
                    mlp1_epi(ng * 2, acc);
                }
                {
                    f32x4 acc[2] = {z4, z4};
                    #pragma unroll
                    for (int kt = 0; kt < 8; ++kt)
                        #pragma unroll
                        for (int m = 0; m < 2; ++m)
                            acc[m] = mfma16(nf[m][kt], bB[kt], acc[m]);
                    mlp1_epi(ng * 2 + 1, acc);
                }
            }
            __syncthreads();   // HM ready

            // MLP2 partial: accumulate HM @ w2[half*256 +: 256, :]; ntg = ng*2 + i
            {
                bf16x8 hf[2][8];
                #pragma unroll
                for (int m = 0; m < 2; ++m)
                    #pragma unroll
                    for (int kt = 0; kt < 8; ++kt)
                        hf[m][kt] = *(const bf16x8*)(smem + OFF_HM + (((mg * 2 + m) * 8 + kt) << 10) + lane * 16);

                bf16x8 bA[8], bB[8];
                #pragma unroll
                for (int kt = 0; kt < 8; ++kt)
                    bA[kt] = *(const bf16x8*)(ws + (size_t)(((WS_W2_BLK + (ng * 2 + 0) * 16 + half * 8 + kt)) << 10) + lane * 16);
                #pragma unroll
                for (int kt = 0; kt < 8; ++kt)
                    bB[kt] = *(const bf16x8*)(ws + (size_t)(((WS_W2_BLK + (ng * 2 + 1) * 16 + half * 8 + kt)) << 10) + lane * 16);
                #pragma unroll
                for (int kt = 0; kt < 8; ++kt)
                    #pragma unroll
                    for (int m = 0; m < 2; ++m)
                        a20[m] = mfma16(hf[m][kt], bA[kt], a20[m]);
                #pragma unroll
                for (int kt = 0; kt < 8; ++kt)
                    #pragma unroll
                    for (int m = 0; m < 2; ++m)
                        a21[m] = mfma16(hf[m][kt], bB[kt], a21[m]);
            }
            __syncthreads();   // HM reads done
        }

        // epilogue: win2 += mlp2 + b2
        auto mlp2_epi = [&](int i, const f32x4 (&acc)[2]) {
            const int c = (ng * 2 + i) * 16 + l15;
            const float bias = b2[c];
            #pragma unroll
            for (int m = 0; m < 2; ++m)
                #pragma unroll
                for (int r = 0; r < 4; ++r) {
                    int t = (mg * 2 + m) * 16 + sub * 4 + r;
                    if (t < TOK) sW[t * SX_ST + c] += acc[m][r] + bias;
                }
        };
        mlp2_epi(0, a20); mlp2_epi(1, a21);
    }
    __syncthreads();   // final

    // ---- P10: window-reverse store ----
    for (int e = tid; e < TOK * CH; e += 1024) {
        int j = e % 7; int rem = e / 7; int i = rem % 7; int c = rem / 7;
        y[xbase + ((size_t)c * IMG + row0 + i) * IMG + col0 + j] = sW[(i * 7 + j) * SX_ST + c];
    }
}

extern "C" void kernel_launch(void* const* d_in, const int* in_sizes, int n_in,
                              void* d_out, int out_size, void* d_ws, size_t ws_size,
                              hipStream_t stream) {
    const float* x      = (const float*)d_in[0];
    const float* ln1_g  = (const float*)d_in[1];
    const float* ln1_b  = (const float*)d_in[2];
    const float* qkv_w  = (const float*)d_in[3];
    const float* qkv_b  = (const float*)d_in[4];
    const float* proj_w = (const float*)d_in[5];
    const float* proj_b = (const float*)d_in[6];
    const float* ln2_g  = (const float*)d_in[7];
    const float* ln2_b  = (const float*)d_in[8];
    const float* w1     = (const float*)d_in[9];
    const float* b1     = (const float*)d_in[10];
    const float* w2     = (const float*)d_in[11];
    const float* b2     = (const float*)d_in[12];

    hipLaunchKernelGGL(prepack, dim3(1024), dim3(64), 0, stream,
                       qkv_w, proj_w, w1, w2, (char*)d_ws);
    hipLaunchKernelGGL(swin_block, dim3(NWIN), dim3(1024), 0, stream,
                       x, ln1_g, ln1_b, qkv_b, proj_b, ln2_g, ln2_b, b1, b2,
                       (const char*)d_ws, (float*)d_out);
}